// Round 1
// baseline (290.660 us; speedup 1.0000x reference)
//
#include <hip/hip_runtime.h>

// ---------------------------------------------------------------------------
// EnsembleTransitionMLP: fused 4-layer MLP over 50 ensembles, bf16 MFMA.
// Pipeline per launch (ws re-poisoned every call, so all pre-passes re-run):
//   1. k_init_flag / k_detect : device-side input-dtype detection (bf16 vs f32)
//   2. k_pack_sa / k_pack_w / k_pack_bias : repack inputs into bf16 fragment-
//      order layouts in d_ws (K padded 40->64 for layer1, N padded 33->48 for
//      layer4, zero fill)
//   3. k_mlp : grid (128 row-blocks x 50 ensembles), 256 thr, BM=64 rows.
//      h kept in 32KB LDS (A-fragment layout), updated in place per layer.
//      Weights read as B-fragments directly from global (L2-resident).
// ---------------------------------------------------------------------------

typedef __attribute__((ext_vector_type(8))) short short8;
typedef __attribute__((ext_vector_type(4))) float floatx4;

#define NE 50
#define NB 8192
#define OUT_NS_ELEMS (NB * NE * 32)

__device__ __forceinline__ unsigned short f2bf(float x) {
  unsigned u = __float_as_uint(x);
  u += 0x7fffu + ((u >> 16) & 1u);   // round-to-nearest-even
  return (unsigned short)(u >> 16);
}
__device__ __forceinline__ float bf2f(unsigned short b) {
  return __uint_as_float(((unsigned)b) << 16);
}
__device__ __forceinline__ floatx4 mfma16(short8 a, short8 b, floatx4 c) {
  return __builtin_amdgcn_mfma_f32_16x16x32_bf16(a, b, c, 0, 0, 0);
}

// ---------------- dtype detection ----------------
__global__ void k_init_flag(int* flag) { *flag = 1; }

// Scan W2's 32-bit words. If the buffer really holds bf16 pairs, every low
// half is a weight ~N(0,0.05^2): |v| < 16 and never exactly 0. If it holds
// f32 (full precision: random low mantissa bits -> some decode huge / some are
// exactly 0; bf16-rounded-then-upcast: low halves all 0), at least one word
// trips a check with probability ~1 over 1.6M words.
__global__ void k_detect(const unsigned* __restrict__ w2raw, int* __restrict__ flag) {
  int tid = blockIdx.x * 256 + threadIdx.x;
  bool bad = false;
  for (int i = tid; i < 1638400; i += 256 * 256) {
    unsigned word = w2raw[i];
    unsigned short lo = (unsigned short)(word & 0xFFFFu);
    float f = bf2f(lo);
    if (!(fabsf(f) < 16.0f)) bad = true;
    if (lo == 0) bad = true;
  }
  if (bad) *flag = 0;  // 0 => inputs are f32; 1 => inputs are bf16
}

__device__ __forceinline__ unsigned short load_bf(const void* p, int i, bool isbf) {
  if (isbf) return ((const unsigned short*)p)[i];
  return f2bf(((const float*)p)[i]);
}
__device__ __forceinline__ float load_f(const void* p, int i, bool isbf) {
  if (isbf) return bf2f(((const unsigned short*)p)[i]);
  return ((const float*)p)[i];
}

// ---------------- packing ----------------
// sa_pack layout (A-fragment order, 16B units):
//   elt = ((mt*8 + kb)*16 + mi)*8 + j ; b = mt*16+mi ; k = kb*8+j (K padded to 64)
__global__ void k_pack_sa(const void* __restrict__ state, const void* __restrict__ action,
                          const int* __restrict__ flag, unsigned short* __restrict__ dst) {
  int gid = blockIdx.x * 256 + threadIdx.x;   // 524288 total
  bool isbf = (*flag != 0);
  int j = gid & 7, mi = (gid >> 3) & 15, kb = (gid >> 7) & 7, mt = gid >> 10;
  int b = mt * 16 + mi, k = kb * 8 + j;
  unsigned short v = 0;
  if (k < 32)      v = load_bf(state,  b * 32 + k,        isbf);
  else if (k < 40) v = load_bf(action, b * 8 + (k - 32),  isbf);
  dst[gid] = v;
}

// W pack layout per ensemble (B-fragment order):
//   i = (((kt*nTilesN + nt)*4 + kb)*16 + ni)*8 + j ; k = kt*32+kb*8+j ; n = nt*16+ni
__global__ void k_pack_w(const void* __restrict__ src, unsigned short* __restrict__ dst,
                         const int* __restrict__ flag, int K, int N, int nTilesN, int perE) {
  int gid = blockIdx.x * 256 + threadIdx.x;
  bool isbf = (*flag != 0);
  int e = gid / perE;
  int i = gid - e * perE;
  int j = i & 7, ni = (i >> 3) & 15, kb = (i >> 7) & 3, t = i >> 9;
  int nt = t % nTilesN, kt = t / nTilesN;
  int k = kt * 32 + kb * 8 + j, n = nt * 16 + ni;
  unsigned short v = 0;
  if (k < K && n < N) v = load_bf(src, (e * K + k) * N + n, isbf);
  dst[gid] = v;
}

// biases as f32: per e: [b1(256)][b2(256)][b3(256)][b4(48, zero-padded)]
__global__ void k_pack_bias(const void* b1, const void* b2, const void* b3, const void* b4,
                            const int* __restrict__ flag, float* __restrict__ dst) {
  int gid = blockIdx.x * 256 + threadIdx.x;
  if (gid >= NE * 816) return;
  bool isbf = (*flag != 0);
  int e = gid / 816, r = gid - e * 816;
  float v = 0.0f;
  if (r < 256)      v = load_f(b1, e * 256 + r,          isbf);
  else if (r < 512) v = load_f(b2, e * 256 + (r - 256),  isbf);
  else if (r < 768) v = load_f(b3, e * 256 + (r - 512),  isbf);
  else { int q = r - 768; if (q < 33) v = load_f(b4, e * 33 + q, isbf); }
  dst[gid] = v;
}

// ---------------- fused MLP ----------------
// LDS: h (A-fragment layout) 32768B at [0..32767]; layer-4 partial-sum overlay
// uses full 51200B after h is dead. 51200B -> 3 blocks/CU.
//
// A-frag (16x16x32): lane holds A[m=l&15][k=(l>>4)*8+j]; unit = mt*512+kt*64+l
// B-frag:            lane holds B[k=(l>>4)*8+j][n=l&15]; packed so unit =
//                    kt*(tilesN*64) + ntg*64 + l  (contiguous per wave read)
// C/D: lane holds D[row=(l>>4)*4+r][col=l&15]

__device__ __forceinline__ void hidden_layer_256(
    const unsigned short* __restrict__ wbase,  // packed W for this e (65536 elts)
    const float* __restrict__ brow,            // bias row (256 f32)
    unsigned char* smem, int w, int l, int li, int g) {
  floatx4 acc[4][4];
  floatx4 z4 = {0.0f, 0.0f, 0.0f, 0.0f};
#pragma unroll
  for (int rt = 0; rt < 4; ++rt)
#pragma unroll
    for (int nt = 0; nt < 4; ++nt) acc[rt][nt] = z4;

  for (int kt = 0; kt < 8; ++kt) {
    short8 a[4], b[4];
#pragma unroll
    for (int nt = 0; nt < 4; ++nt)
      b[nt] = *(const short8*)(wbase + (kt * 1024 + (w * 4 + nt) * 64 + l) * 8);
#pragma unroll
    for (int rt = 0; rt < 4; ++rt)
      a[rt] = *(const short8*)(smem + (rt * 512 + kt * 64 + l) * 16);
#pragma unroll
    for (int rt = 0; rt < 4; ++rt)
#pragma unroll
      for (int nt = 0; nt < 4; ++nt)
        acc[rt][nt] = mfma16(a[rt], b[nt], acc[rt][nt]);
  }
  __syncthreads();  // all reads of h done before in-place overwrite
#pragma unroll
  for (int nt = 0; nt < 4; ++nt) {
    int kcol = w * 64 + nt * 16 + li;
    float bv = brow[kcol];
    int kb = kcol >> 3, j = kcol & 7;
#pragma unroll
    for (int rt = 0; rt < 4; ++rt)
#pragma unroll
      for (int r = 0; r < 4; ++r) {
        float v = fmaxf(acc[rt][nt][r] + bv, 0.0f);
        *(unsigned short*)(smem + rt * 8192 + kb * 256 + (g * 4 + r) * 16 + j * 2) = f2bf(v);
      }
  }
  __syncthreads();
}

__global__ __launch_bounds__(256, 3) void k_mlp(
    const unsigned short* __restrict__ sa,
    const unsigned short* __restrict__ w1,
    const unsigned short* __restrict__ w2,
    const unsigned short* __restrict__ w3,
    const unsigned short* __restrict__ w4,
    const float* __restrict__ bias,
    const int* __restrict__ flag,
    void* __restrict__ outp) {
  __shared__ __attribute__((aligned(16))) unsigned char smem[51200];
  const int tid = threadIdx.x;
  const int w = tid >> 6, l = tid & 63, li = l & 15, g = l >> 4;
  const int bb = blockIdx.x;  // 64-row batch tile
  const int e  = blockIdx.y;  // ensemble
  const float* brow = bias + e * 816;

  // ---- layer 1: sa(64x64) x W1(64x256) -> h1 in LDS ----
  {
    floatx4 acc[4][4];
    floatx4 z4 = {0.0f, 0.0f, 0.0f, 0.0f};
#pragma unroll
    for (int rt = 0; rt < 4; ++rt)
#pragma unroll
      for (int nt = 0; nt < 4; ++nt) acc[rt][nt] = z4;

#pragma unroll
    for (int kt = 0; kt < 2; ++kt) {
      short8 a[4], b[4];
#pragma unroll
      for (int rt = 0; rt < 4; ++rt)
        a[rt] = *(const short8*)(sa + ((bb * 4 + rt) * 128 + kt * 64 + l) * 8);
#pragma unroll
      for (int nt = 0; nt < 4; ++nt)
        b[nt] = *(const short8*)(w1 + (e * 2048 + kt * 1024 + (w * 4 + nt) * 64 + l) * 8);
#pragma unroll
      for (int rt = 0; rt < 4; ++rt)
#pragma unroll
        for (int nt = 0; nt < 4; ++nt)
          acc[rt][nt] = mfma16(a[rt], b[nt], acc[rt][nt]);
    }
    // epilogue (no prior LDS readers; barrier only after writes)
#pragma unroll
    for (int nt = 0; nt < 4; ++nt) {
      int kcol = w * 64 + nt * 16 + li;
      float bv = brow[kcol];
      int kb = kcol >> 3, j = kcol & 7;
#pragma unroll
      for (int rt = 0; rt < 4; ++rt)
#pragma unroll
        for (int r = 0; r < 4; ++r) {
          float v = fmaxf(acc[rt][nt][r] + bv, 0.0f);
          *(unsigned short*)(smem + rt * 8192 + kb * 256 + (g * 4 + r) * 16 + j * 2) = f2bf(v);
        }
    }
    __syncthreads();
  }

  // ---- layers 2, 3 ----
  hidden_layer_256(w2 + (size_t)e * 65536, brow + 256, smem, w, l, li, g);
  hidden_layer_256(w3 + (size_t)e * 65536, brow + 512, smem, w, l, li, g);

  // ---- layer 4: h3(64x256) x W4(256x48) -> out, split-K across waves ----
  floatx4 acc4[4][3];
  {
    floatx4 z4 = {0.0f, 0.0f, 0.0f, 0.0f};
#pragma unroll
    for (int rt = 0; rt < 4; ++rt)
#pragma unroll
      for (int nt = 0; nt < 3; ++nt) acc4[rt][nt] = z4;
  }
#pragma unroll
  for (int rep = 0; rep < 2; ++rep) {
    int kt = w * 2 + rep;
    short8 a[4], b[3];
#pragma unroll
    for (int nt = 0; nt < 3; ++nt)
      b[nt] = *(const short8*)(w4 + (e * 1536 + kt * 192 + nt * 64 + l) * 8);
#pragma unroll
    for (int rt = 0; rt < 4; ++rt)
      a[rt] = *(const short8*)(smem + (rt * 512 + kt * 64 + l) * 16);
#pragma unroll
    for (int rt = 0; rt < 4; ++rt)
#pragma unroll
      for (int nt = 0; nt < 3; ++nt)
        acc4[rt][nt] = mfma16(a[rt], b[nt], acc4[rt][nt]);
  }
  __syncthreads();  // h3 dead; reuse whole LDS for partials (stride 50 words)
#pragma unroll
  for (int rt = 0; rt < 4; ++rt)
#pragma unroll
    for (int nt = 0; nt < 3; ++nt)
#pragma unroll
      for (int r = 0; r < 4; ++r)
        *(float*)(smem + w * 12800 + (rt * 16 + g * 4 + r) * 200 + (nt * 16 + li) * 4) =
            acc4[rt][nt][r];
  __syncthreads();

  const bool isbf = (*flag != 0);
  const float* brow4 = brow + 768;
  for (int idx = tid; idx < 64 * 33; idx += 256) {
    int m = idx / 33;
    int n = idx - m * 33;
    float v = brow4[n];
#pragma unroll
    for (int ww = 0; ww < 4; ++ww)
      v += *(const float*)(smem + ww * 12800 + m * 200 + n * 4);
    int b = bb * 64 + m;
    int o = (n < 32) ? ((b * NE + e) * 32 + n) : (OUT_NS_ELEMS + b * NE + e);
    if (isbf) ((unsigned short*)outp)[o] = f2bf(v);
    else      ((float*)outp)[o] = v;
  }
}

// ---------------------------------------------------------------------------
extern "C" void kernel_launch(void* const* d_in, const int* in_sizes, int n_in,
                              void* d_out, int out_size, void* d_ws, size_t ws_size,
                              hipStream_t stream) {
  const void* state  = d_in[0];
  const void* action = d_in[1];
  const void* W1 = d_in[2];
  const void* b1 = d_in[3];
  const void* W2 = d_in[4];
  const void* b2 = d_in[5];
  const void* W3 = d_in[6];
  const void* b3 = d_in[7];
  const void* W4 = d_in[8];
  const void* b4 = d_in[9];
  (void)in_sizes; (void)n_in; (void)out_size; (void)ws_size;

  char* ws = (char*)d_ws;
  int* flag              = (int*)(ws + 0);
  unsigned short* saP    = (unsigned short*)(ws + 256);        // 1,048,576 B
  unsigned short* w1P    = (unsigned short*)(ws + 1048832);    // 1,638,400 B
  unsigned short* w2P    = (unsigned short*)(ws + 2687232);    // 6,553,600 B
  unsigned short* w3P    = (unsigned short*)(ws + 9240832);    // 6,553,600 B
  unsigned short* w4P    = (unsigned short*)(ws + 15794432);   // 1,228,800 B
  float* biasP           = (float*)(ws + 17023232);            //   163,200 B
  // total ws use: 17,186,432 B

  k_init_flag<<<1, 1, 0, stream>>>(flag);
  k_detect<<<256, 256, 0, stream>>>((const unsigned*)W2, flag);
  k_pack_sa<<<2048, 256, 0, stream>>>(state, action, flag, saP);
  k_pack_w<<<3200, 256, 0, stream>>>(W1, w1P, flag, 40, 256, 16, 16384);
  k_pack_w<<<12800, 256, 0, stream>>>(W2, w2P, flag, 256, 256, 16, 65536);
  k_pack_w<<<12800, 256, 0, stream>>>(W3, w3P, flag, 256, 256, 16, 65536);
  k_pack_w<<<2400, 256, 0, stream>>>(W4, w4P, flag, 256, 33, 3, 12288);
  k_pack_bias<<<160, 256, 0, stream>>>(b1, b2, b3, b4, flag, biasP);
  k_mlp<<<dim3(128, 50), 256, 0, stream>>>(saP, w1P, w2P, w3P, w4P, biasP, flag, d_out);
}

// Round 2
// 268.104 us; speedup vs baseline: 1.0841x; 1.0841x over previous
//
#include <hip/hip_runtime.h>

// ---------------------------------------------------------------------------
// EnsembleTransitionMLP: fused 4-layer MLP over 50 ensembles, bf16 MFMA.
// Round 2:
//  - transpose trick: compute h^T = W^T * h^T by swapping mfma operands; the
//    C-layout then has consecutive FEATURES per lane -> epilogue packs 4 bf16
//    into one ds_write_b64 (was 64 ds_write_b16 per thread per layer).
//  - bias folded into accumulator init; ReLU+cvt = fmax + (u+0x8000) + v_perm.
//  - layer 4 partitioned by batch tile per wave (no split-K, no LDS reduce):
//    LDS = 32KB -> 4 blocks/CU (launch_bounds(256,4)).
//  - single mega-pack pre-pass kernel (LDS-transpose panels, coalesced both
//    sides) replaces 6 separate pack launches.
// ---------------------------------------------------------------------------

typedef __attribute__((ext_vector_type(8))) short short8;
typedef __attribute__((ext_vector_type(4))) float floatx4;

#define NE 50
#define NB 8192
#define OUT_NS_ELEMS (NB * NE * 32)

__device__ __forceinline__ unsigned short f2bf_rne(float x) {
  unsigned u = __float_as_uint(x);
  u += 0x7fffu + ((u >> 16) & 1u);
  return (unsigned short)(u >> 16);
}
__device__ __forceinline__ float bf2f(unsigned short b) {
  return __uint_as_float(((unsigned)b) << 16);
}
__device__ __forceinline__ floatx4 mfma16(short8 a, short8 b, floatx4 c) {
  return __builtin_amdgcn_mfma_f32_16x16x32_bf16(a, b, c, 0, 0, 0);
}
// pack two f32 -> one dword of bf16 pair, round-half-up (cheap, <=1/2 ulp bias)
__device__ __forceinline__ unsigned pack_bf2(float lo, float hi) {
  unsigned u0 = __float_as_uint(lo) + 0x8000u;
  unsigned u1 = __float_as_uint(hi) + 0x8000u;
  return __builtin_amdgcn_perm(u1, u0, 0x07060302u);  // [u0.hi16, u1.hi16]
}

// ---------------- dtype detection ----------------
__global__ void k_init_flag(int* flag) { *flag = 1; }

__global__ void k_detect(const unsigned* __restrict__ w2raw, int* __restrict__ flag) {
  int tid = blockIdx.x * 256 + threadIdx.x;
  bool bad = false;
  for (int i = tid; i < 1638400; i += 256 * 256) {
    unsigned word = w2raw[i];
    unsigned short lo = (unsigned short)(word & 0xFFFFu);
    float f = bf2f(lo);
    if (!(fabsf(f) < 16.0f)) bad = true;
    if (lo == 0) bad = true;
  }
  if (bad) *flag = 0;  // 0 => f32 inputs; 1 => bf16 inputs
}

__device__ __forceinline__ unsigned short load_bf(const void* p, long i, bool isbf) {
  if (isbf) return ((const unsigned short*)p)[i];
  return f2bf_rne(((const float*)p)[i]);
}
__device__ __forceinline__ float load_f(const void* p, long i, bool isbf) {
  if (isbf) return bf2f(((const unsigned short*)p)[i]);
  return ((const float*)p)[i];
}

// ---------------- mega pack ----------------
// W pack layout per ensemble (B-fragment order):
//   elt = (((kt*NT + nt)*4 + kb)*16 + ni)*8 + j ; k = kt*32+kb*8+j ; n = nt*16+ni
// Block = one (matrix, e, kt) panel: stage 32 x Npad to LDS coalesced, emit
// 16B fragment units coalesced. LDS row stride Npad+10 shorts: the kb groups
// (8 rows * stride) land 8 banks apart -> conflict-free unit reads.
__device__ void pack_w_panel(const void* __restrict__ src, unsigned short* __restrict__ dst,
                             bool isbf, int e, int kt, int K, int N, int NT, int perE,
                             unsigned short* lds) {
  const int t = threadIdx.x;
  const int Npad = NT * 16;
  const int NP = Npad + 10;
  for (int idx = t; idx < 32 * Npad; idx += 256) {
    int r = idx / Npad, c = idx - r * Npad;
    int k = kt * 32 + r;
    unsigned short v = 0;
    if (k < K && c < N) v = load_bf(src, (long)(e * K + k) * N + c, isbf);
    lds[r * NP + c] = v;
  }
  __syncthreads();
  for (int u = t; u < NT * 64; u += 256) {
    int nt = u >> 6, kb = (u >> 4) & 3, ni = u & 15;
    int n = nt * 16 + ni;
    unsigned v[4];
#pragma unroll
    for (int p = 0; p < 4; ++p) {
      unsigned lo = lds[(kb * 8 + 2 * p) * NP + n];
      unsigned hi = lds[(kb * 8 + 2 * p + 1) * NP + n];
      v[p] = lo | (hi << 16);
    }
    long off = (long)e * perE + ((long)((kt * NT + nt) * 64 + kb * 16 + ni)) * 8;
    *(uint4*)(dst + off) = make_uint4(v[0], v[1], v[2], v[3]);
  }
}

__global__ void k_pack(const void* __restrict__ state, const void* __restrict__ action,
                       const void* __restrict__ W1, const void* __restrict__ W2,
                       const void* __restrict__ W3, const void* __restrict__ W4,
                       const void* __restrict__ b1, const void* __restrict__ b2,
                       const void* __restrict__ b3, const void* __restrict__ b4,
                       const int* __restrict__ flag,
                       unsigned short* __restrict__ saP, unsigned short* __restrict__ w1P,
                       unsigned short* __restrict__ w2P, unsigned short* __restrict__ w3P,
                       unsigned short* __restrict__ w4P, float* __restrict__ biasP) {
  __shared__ unsigned short lds[32 * 266];  // 17,024 B
  const bool isbf = (*flag != 0);
  const int b = blockIdx.x;
  if (b < 400) {
    pack_w_panel(W2, w2P, isbf, b >> 3, b & 7, 256, 256, 16, 65536, lds);
  } else if (b < 800) {
    int bb = b - 400;
    pack_w_panel(W3, w3P, isbf, bb >> 3, bb & 7, 256, 256, 16, 65536, lds);
  } else if (b < 900) {
    int bb = b - 800;
    pack_w_panel(W1, w1P, isbf, bb >> 1, bb & 1, 40, 256, 16, 16384, lds);
  } else if (b < 1300) {
    int bb = b - 900;
    pack_w_panel(W4, w4P, isbf, bb >> 3, bb & 7, 256, 33, 3, 12288, lds);
  } else if (b < 1556) {
    // sa pack (A-frag order): unit u: mi=u&15, kb=(u>>4)&7, mt=u>>7
    int u = (b - 1300) * 256 + threadIdx.x;  // < 65536
    int mi = u & 15, kb = (u >> 4) & 7, mt = u >> 7;
    int row = mt * 16 + mi;
    unsigned v[4] = {0u, 0u, 0u, 0u};
    if (kb < 4) {
#pragma unroll
      for (int p = 0; p < 4; ++p) {
        unsigned lo = load_bf(state, (long)row * 32 + kb * 8 + 2 * p, isbf);
        unsigned hi = load_bf(state, (long)row * 32 + kb * 8 + 2 * p + 1, isbf);
        v[p] = lo | (hi << 16);
      }
    } else if (kb == 4) {
#pragma unroll
      for (int p = 0; p < 4; ++p) {
        unsigned lo = load_bf(action, (long)row * 8 + 2 * p, isbf);
        unsigned hi = load_bf(action, (long)row * 8 + 2 * p + 1, isbf);
        v[p] = lo | (hi << 16);
      }
    }
    *(uint4*)(saP + (long)u * 8) = make_uint4(v[0], v[1], v[2], v[3]);
  } else {
    // bias: per e: [b1(256)][b2(256)][b3(256)][b4(48 zero-padded)]
    int gid = (b - 1556) * 256 + threadIdx.x;
    if (gid < NE * 816) {
      int e = gid / 816, r = gid - e * 816;
      float v = 0.0f;
      if (r < 256)      v = load_f(b1, e * 256 + r,         isbf);
      else if (r < 512) v = load_f(b2, e * 256 + (r - 256), isbf);
      else if (r < 768) v = load_f(b3, e * 256 + (r - 512), isbf);
      else { int q = r - 768; if (q < 33) v = load_f(b4, e * 33 + q, isbf); }
      biasP[gid] = v;
    }
  }
}

// ---------------- fused MLP ----------------
// h^T in LDS (32KB), B-fragment layout: element (k=feat, n=batch) at short
// index ((k>>5)*4 + (n>>4))*512 + ((k>>3)&3)*128 + (n&15)*8 + (k&7).
// Fragment read for tile (kt, bt): lane l reads 16B at unit (kt*4+bt)*64 + l.
// C-layout after operand swap: lane holds D[feat=(l>>4)*4+r][batch=l&15]:
// 4 consecutive feats -> one ds_write_b64.

__device__ __forceinline__ void store_hT(const floatx4 (&acc)[4][4], unsigned short* hT,
                                         int w, int li, int g) {
#pragma unroll
  for (int ot = 0; ot < 4; ++ot) {
    int k0 = w * 64 + ot * 16 + g * 4;
    int base = ((k0 >> 5) * 4) * 512 + ((k0 >> 3) & 3) * 128 + li * 8 + (k0 & 7);
#pragma unroll
    for (int bt = 0; bt < 4; ++bt) {
      float v0 = fmaxf(acc[ot][bt][0], 0.0f);
      float v1 = fmaxf(acc[ot][bt][1], 0.0f);
      float v2 = fmaxf(acc[ot][bt][2], 0.0f);
      float v3 = fmaxf(acc[ot][bt][3], 0.0f);
      unsigned d0 = pack_bf2(v0, v1);
      unsigned d1 = pack_bf2(v2, v3);
      *(unsigned long long*)(hT + base + bt * 512) =
          (unsigned long long)d0 | ((unsigned long long)d1 << 32);
    }
  }
}

__device__ __forceinline__ void bias_init(floatx4 (&acc)[4][4], const float* br,
                                          int w, int g) {
#pragma unroll
  for (int ot = 0; ot < 4; ++ot) {
    const float4 b4 = *(const float4*)(br + w * 64 + ot * 16 + g * 4);
    floatx4 iv = {b4.x, b4.y, b4.z, b4.w};
#pragma unroll
    for (int bt = 0; bt < 4; ++bt) acc[ot][bt] = iv;
  }
}

__device__ __forceinline__ void hidden_layer(const unsigned short* __restrict__ wb,
                                             const float* __restrict__ br,
                                             unsigned short* hT, int w, int l, int li, int g) {
  floatx4 acc[4][4];
  bias_init(acc, br, w, g);
  for (int kt = 0; kt < 8; ++kt) {
    short8 a[4], b[4];
#pragma unroll
    for (int ot = 0; ot < 4; ++ot)
      a[ot] = *(const short8*)(wb + (long)((kt * 16 + w * 4 + ot) * 64 + l) * 8);
#pragma unroll
    for (int bt = 0; bt < 4; ++bt)
      b[bt] = *(const short8*)(hT + ((kt * 4 + bt) * 64 + l) * 8);
#pragma unroll
    for (int ot = 0; ot < 4; ++ot)
#pragma unroll
      for (int bt = 0; bt < 4; ++bt)
        acc[ot][bt] = mfma16(a[ot], b[bt], acc[ot][bt]);  // A=W^T, B=h^T
  }
  __syncthreads();  // all reads of hT done before in-place overwrite
  store_hT(acc, hT, w, li, g);
  __syncthreads();
}

__global__ __launch_bounds__(256, 4) void k_mlp(
    const unsigned short* __restrict__ sa,
    const unsigned short* __restrict__ w1,
    const unsigned short* __restrict__ w2,
    const unsigned short* __restrict__ w3,
    const unsigned short* __restrict__ w4,
    const float* __restrict__ bias,
    const int* __restrict__ flag,
    void* __restrict__ outp) {
  __shared__ __attribute__((aligned(16))) unsigned short hT[16384];  // 32 KB
  const int tid = threadIdx.x;
  const int w = tid >> 6, l = tid & 63, li = l & 15, g = l >> 4;
  const int bb = blockIdx.x;  // 64-row batch tile
  const int e  = blockIdx.y;  // ensemble
  const float* brow = bias + e * 816;
  const bool isbf = (*flag != 0);

  // ---- layer 1: W1^T(256x64) * sa^T(64x64) -> h1^T in LDS ----
  {
    floatx4 acc[4][4];
    bias_init(acc, brow, w, g);
#pragma unroll
    for (int kt = 0; kt < 2; ++kt) {
      short8 a[4], b[4];
#pragma unroll
      for (int ot = 0; ot < 4; ++ot)
        a[ot] = *(const short8*)(w1 + (long)e * 16384 + (long)((kt * 16 + w * 4 + ot) * 64 + l) * 8);
#pragma unroll
      for (int bt = 0; bt < 4; ++bt)
        b[bt] = *(const short8*)(sa + (long)((bb * 4 + bt) * 128 + kt * 64 + l) * 8);
#pragma unroll
      for (int ot = 0; ot < 4; ++ot)
#pragma unroll
        for (int bt = 0; bt < 4; ++bt)
          acc[ot][bt] = mfma16(a[ot], b[bt], acc[ot][bt]);
    }
    store_hT(acc, hT, w, li, g);
    __syncthreads();
  }

  // ---- layers 2, 3 ----
  hidden_layer(w2 + (long)e * 65536, brow + 256, hT, w, l, li, g);
  hidden_layer(w3 + (long)e * 65536, brow + 512, hT, w, l, li, g);

  // ---- layer 4: W4^T(48x256) * h3^T(256x64), wave w owns batch tile w ----
  const float* brow4 = brow + 768;
  floatx4 acc4[3];
#pragma unroll
  for (int ot = 0; ot < 3; ++ot) {
    const float4 b4 = *(const float4*)(brow4 + ot * 16 + g * 4);
    acc4[ot] = (floatx4){b4.x, b4.y, b4.z, b4.w};
  }
  for (int kt = 0; kt < 8; ++kt) {
    short8 bfrag = *(const short8*)(hT + ((kt * 4 + w) * 64 + l) * 8);
#pragma unroll
    for (int ot = 0; ot < 3; ++ot) {
      short8 a = *(const short8*)(w4 + (long)e * 12288 + (long)((kt * 3 + ot) * 64 + l) * 8);
      acc4[ot] = mfma16(a, bfrag, acc4[ot]);
    }
  }

  // ---- output: lane holds out[feat=ot*16+g*4+r][batch=bb*64+w*16+li] ----
  const int batch = bb * 64 + w * 16 + li;
  const long nsbase = (long)(batch * NE + e) * 32;
  if (isbf) {
    unsigned short* o16 = (unsigned short*)outp;
#pragma unroll
    for (int ot = 0; ot < 2; ++ot) {
      unsigned d0 = pack_bf2(acc4[ot][0], acc4[ot][1]);
      unsigned d1 = pack_bf2(acc4[ot][2], acc4[ot][3]);
      *(unsigned long long*)(o16 + nsbase + ot * 16 + g * 4) =
          (unsigned long long)d0 | ((unsigned long long)d1 << 32);
    }
    if (g == 0) {  // reward = feat 32
      unsigned u = __float_as_uint(acc4[2][0]) + 0x8000u;
      o16[OUT_NS_ELEMS + batch * NE + e] = (unsigned short)(u >> 16);
    }
  } else {
    float* o32 = (float*)outp;
#pragma unroll
    for (int ot = 0; ot < 2; ++ot)
      *(float4*)(o32 + nsbase + ot * 16 + g * 4) =
          make_float4(acc4[ot][0], acc4[ot][1], acc4[ot][2], acc4[ot][3]);
    if (g == 0) o32[OUT_NS_ELEMS + batch * NE + e] = acc4[2][0];
  }
}

// ---------------------------------------------------------------------------
extern "C" void kernel_launch(void* const* d_in, const int* in_sizes, int n_in,
                              void* d_out, int out_size, void* d_ws, size_t ws_size,
                              hipStream_t stream) {
  const void* state  = d_in[0];
  const void* action = d_in[1];
  const void* W1 = d_in[2];
  const void* b1 = d_in[3];
  const void* W2 = d_in[4];
  const void* b2 = d_in[5];
  const void* W3 = d_in[6];
  const void* b3 = d_in[7];
  const void* W4 = d_in[8];
  const void* b4 = d_in[9];
  (void)in_sizes; (void)n_in; (void)out_size; (void)ws_size;

  char* ws = (char*)d_ws;
  int* flag              = (int*)(ws + 0);
  unsigned short* saP    = (unsigned short*)(ws + 256);        // 1,048,576 B
  unsigned short* w1P    = (unsigned short*)(ws + 1048832);    // 1,638,400 B
  unsigned short* w2P    = (unsigned short*)(ws + 2687232);    // 6,553,600 B
  unsigned short* w3P    = (unsigned short*)(ws + 9240832);    // 6,553,600 B
  unsigned short* w4P    = (unsigned short*)(ws + 15794432);   // 1,228,800 B
  float* biasP           = (float*)(ws + 17023232);            //   163,200 B

  k_init_flag<<<1, 1, 0, stream>>>(flag);
  k_detect<<<256, 256, 0, stream>>>((const unsigned*)W2, flag);
  k_pack<<<1716, 256, 0, stream>>>(state, action, W1, W2, W3, W4, b1, b2, b3, b4,
                                   flag, saP, w1P, w2P, w3P, w4P, biasP);
  k_mlp<<<dim3(128, 50), 256, 0, stream>>>(saP, w1P, w2P, w3P, w4P, biasP, flag, d_out);
}

// Round 3
// 261.392 us; speedup vs baseline: 1.1120x; 1.0257x over previous
//
#include <hip/hip_runtime.h>

// ---------------------------------------------------------------------------
// EnsembleTransitionMLP: fused 4-layer MLP over 50 ensembles, bf16 MFMA.
// Round 3:
//  - BM=128 per block (512 thr, 8 waves = 4 feat-strips x 2 batch-strips),
//    hT = 64KB LDS, 2 blocks/CU: halves weight re-read traffic and barrier
//    count per FLOP vs BM=64.
//  - depth-1 software prefetch of next-kt weight fragments (global) in the
//    hidden-layer K-loop; launch_bounds(512,4) -> 128 VGPR budget.
//  - pre-pass trimmed to 2 launches: sampling k_detect (2048 words, folds
//    flag init) + mega k_pack.
// ---------------------------------------------------------------------------

typedef __attribute__((ext_vector_type(8))) short short8;
typedef __attribute__((ext_vector_type(4))) float floatx4;

#define NE 50
#define NB 8192
#define OUT_NS_ELEMS (NB * NE * 32)

__device__ __forceinline__ unsigned short f2bf_rne(float x) {
  unsigned u = __float_as_uint(x);
  u += 0x7fffu + ((u >> 16) & 1u);
  return (unsigned short)(u >> 16);
}
__device__ __forceinline__ float bf2f(unsigned short b) {
  return __uint_as_float(((unsigned)b) << 16);
}
__device__ __forceinline__ floatx4 mfma16(short8 a, short8 b, floatx4 c) {
  return __builtin_amdgcn_mfma_f32_16x16x32_bf16(a, b, c, 0, 0, 0);
}
// pack two f32 -> one dword of bf16 pair, round-half-up
__device__ __forceinline__ unsigned pack_bf2(float lo, float hi) {
  unsigned u0 = __float_as_uint(lo) + 0x8000u;
  unsigned u1 = __float_as_uint(hi) + 0x8000u;
  return __builtin_amdgcn_perm(u1, u0, 0x07060302u);  // [u0.hi16, u1.hi16]
}

// ---------------- dtype detection (flag init folded in) ----------------
// Sample 2048 words of W2. bf16 data: every low half decodes |v|<16 and !=0.
// f32 data: random low mantissa halves pass that test w.p. ~0.51 each ->
// P(false positive) ~ 0.51^2048 ~ 0.
__global__ void k_detect(const unsigned* __restrict__ w2raw, int* __restrict__ flag) {
  __shared__ int s_bad;
  if (threadIdx.x == 0) s_bad = 0;
  __syncthreads();
  bool bad = false;
  for (int i = threadIdx.x; i < 2048; i += 256) {
    unsigned word = w2raw[i * 797];  // spread samples across the buffer
    unsigned short lo = (unsigned short)(word & 0xFFFFu);
    float f = bf2f(lo);
    if (!(fabsf(f) < 16.0f)) bad = true;
    if (lo == 0) bad = true;
  }
  if (bad) s_bad = 1;
  __syncthreads();
  if (threadIdx.x == 0) *flag = s_bad ? 0 : 1;  // 1 => bf16 inputs
}

__device__ __forceinline__ unsigned short load_bf(const void* p, long i, bool isbf) {
  if (isbf) return ((const unsigned short*)p)[i];
  return f2bf_rne(((const float*)p)[i]);
}
__device__ __forceinline__ float load_f(const void* p, long i, bool isbf) {
  if (isbf) return bf2f(((const unsigned short*)p)[i]);
  return ((const float*)p)[i];
}

// ---------------- mega pack ----------------
// W pack layout per ensemble (B-fragment order):
//   elt = (((kt*NT + nt)*4 + kb)*16 + ni)*8 + j ; k = kt*32+kb*8+j ; n = nt*16+ni
__device__ void pack_w_panel(const void* __restrict__ src, unsigned short* __restrict__ dst,
                             bool isbf, int e, int kt, int K, int N, int NT, int perE,
                             unsigned short* lds) {
  const int t = threadIdx.x;
  const int Npad = NT * 16;
  const int NP = Npad + 10;
  for (int idx = t; idx < 32 * Npad; idx += 256) {
    int r = idx / Npad, c = idx - r * Npad;
    int k = kt * 32 + r;
    unsigned short v = 0;
    if (k < K && c < N) v = load_bf(src, (long)(e * K + k) * N + c, isbf);
    lds[r * NP + c] = v;
  }
  __syncthreads();
  for (int u = t; u < NT * 64; u += 256) {
    int nt = u >> 6, kb = (u >> 4) & 3, ni = u & 15;
    int n = nt * 16 + ni;
    unsigned v[4];
#pragma unroll
    for (int p = 0; p < 4; ++p) {
      unsigned lo = lds[(kb * 8 + 2 * p) * NP + n];
      unsigned hi = lds[(kb * 8 + 2 * p + 1) * NP + n];
      v[p] = lo | (hi << 16);
    }
    long off = (long)e * perE + ((long)((kt * NT + nt) * 64 + kb * 16 + ni)) * 8;
    *(uint4*)(dst + off) = make_uint4(v[0], v[1], v[2], v[3]);
  }
}

__global__ void k_pack(const void* __restrict__ state, const void* __restrict__ action,
                       const void* __restrict__ W1, const void* __restrict__ W2,
                       const void* __restrict__ W3, const void* __restrict__ W4,
                       const void* __restrict__ b1, const void* __restrict__ b2,
                       const void* __restrict__ b3, const void* __restrict__ b4,
                       const int* __restrict__ flag,
                       unsigned short* __restrict__ saP, unsigned short* __restrict__ w1P,
                       unsigned short* __restrict__ w2P, unsigned short* __restrict__ w3P,
                       unsigned short* __restrict__ w4P, float* __restrict__ biasP) {
  __shared__ unsigned short lds[32 * 266];  // 17,024 B
  const bool isbf = (*flag != 0);
  const int b = blockIdx.x;
  if (b < 400) {
    pack_w_panel(W2, w2P, isbf, b >> 3, b & 7, 256, 256, 16, 65536, lds);
  } else if (b < 800) {
    int bb = b - 400;
    pack_w_panel(W3, w3P, isbf, bb >> 3, bb & 7, 256, 256, 16, 65536, lds);
  } else if (b < 900) {
    int bb = b - 800;
    pack_w_panel(W1, w1P, isbf, bb >> 1, bb & 1, 40, 256, 16, 16384, lds);
  } else if (b < 1300) {
    int bb = b - 900;
    pack_w_panel(W4, w4P, isbf, bb >> 3, bb & 7, 256, 33, 3, 12288, lds);
  } else if (b < 1556) {
    // sa pack (A-frag order): unit u: mi=u&15, kb=(u>>4)&7, mt=u>>7
    int u = (b - 1300) * 256 + threadIdx.x;  // < 65536
    int mi = u & 15, kb = (u >> 4) & 7, mt = u >> 7;
    int row = mt * 16 + mi;
    unsigned v[4] = {0u, 0u, 0u, 0u};
    if (kb < 4) {
#pragma unroll
      for (int p = 0; p < 4; ++p) {
        unsigned lo = load_bf(state, (long)row * 32 + kb * 8 + 2 * p, isbf);
        unsigned hi = load_bf(state, (long)row * 32 + kb * 8 + 2 * p + 1, isbf);
        v[p] = lo | (hi << 16);
      }
    } else if (kb == 4) {
#pragma unroll
      for (int p = 0; p < 4; ++p) {
        unsigned lo = load_bf(action, (long)row * 8 + 2 * p, isbf);
        unsigned hi = load_bf(action, (long)row * 8 + 2 * p + 1, isbf);
        v[p] = lo | (hi << 16);
      }
    }
    *(uint4*)(saP + (long)u * 8) = make_uint4(v[0], v[1], v[2], v[3]);
  } else {
    // bias: per e: [b1(256)][b2(256)][b3(256)][b4(48 zero-padded)]
    int gid = (b - 1556) * 256 + threadIdx.x;
    if (gid < NE * 816) {
      int e = gid / 816, r = gid - e * 816;
      float v = 0.0f;
      if (r < 256)      v = load_f(b1, e * 256 + r,         isbf);
      else if (r < 512) v = load_f(b2, e * 256 + (r - 256), isbf);
      else if (r < 768) v = load_f(b3, e * 256 + (r - 512), isbf);
      else { int q = r - 768; if (q < 33) v = load_f(b4, e * 33 + q, isbf); }
      biasP[gid] = v;
    }
  }
}

// ---------------- fused MLP ----------------
// BM=128. 512 threads = 8 waves: wf = w&3 (64-feature strip), wb = w>>2
// (64-batch strip). hT in LDS (64KB), B-fragment layout, batch tiles 0..7:
//   short addr(k,b) = ((k>>5)*8 + (b>>4))*512 + ((k>>3)&3)*128 + (b&15)*8 + (k&7)
// C-layout after operand swap: lane holds D[feat=(l>>4)*4+r][batch=l&15]:
// 4 consecutive feats -> one ds_write_b64.

__device__ __forceinline__ void store_hT(const floatx4 (&acc)[4][4], unsigned short* hT,
                                         int wf, int wb, int li, int g) {
#pragma unroll
  for (int ot = 0; ot < 4; ++ot) {
    int k0 = wf * 64 + ot * 16 + g * 4;
    int base = ((k0 >> 5) * 8) * 512 + ((k0 >> 3) & 3) * 128 + li * 8 + (k0 & 7);
#pragma unroll
    for (int bt = 0; bt < 4; ++bt) {
      float v0 = fmaxf(acc[ot][bt][0], 0.0f);
      float v1 = fmaxf(acc[ot][bt][1], 0.0f);
      float v2 = fmaxf(acc[ot][bt][2], 0.0f);
      float v3 = fmaxf(acc[ot][bt][3], 0.0f);
      unsigned d0 = pack_bf2(v0, v1);
      unsigned d1 = pack_bf2(v2, v3);
      *(unsigned long long*)(hT + base + (wb * 4 + bt) * 512) =
          (unsigned long long)d0 | ((unsigned long long)d1 << 32);
    }
  }
}

__device__ __forceinline__ void bias_init(floatx4 (&acc)[4][4], const float* br,
                                          int wf, int g) {
#pragma unroll
  for (int ot = 0; ot < 4; ++ot) {
    const float4 b4 = *(const float4*)(br + wf * 64 + ot * 16 + g * 4);
    floatx4 iv = {b4.x, b4.y, b4.z, b4.w};
#pragma unroll
    for (int bt = 0; bt < 4; ++bt) acc[ot][bt] = iv;
  }
}

__device__ __forceinline__ void hidden_layer(const unsigned short* __restrict__ wb_ptr,
                                             const float* __restrict__ br,
                                             unsigned short* hT,
                                             int wf, int wb, int l, int li, int g) {
  floatx4 acc[4][4];
  bias_init(acc, br, wf, g);
  short8 a[4], an[4], b[4];
#pragma unroll
  for (int ot = 0; ot < 4; ++ot)
    a[ot] = *(const short8*)(wb_ptr + (long)((0 * 16 + wf * 4 + ot) * 64 + l) * 8);
#pragma unroll
  for (int kt = 0; kt < 8; ++kt) {
    if (kt < 7) {
#pragma unroll
      for (int ot = 0; ot < 4; ++ot)
        an[ot] = *(const short8*)(wb_ptr + (long)(((kt + 1) * 16 + wf * 4 + ot) * 64 + l) * 8);
    }
#pragma unroll
    for (int bt = 0; bt < 4; ++bt)
      b[bt] = *(const short8*)(hT + ((kt * 8 + wb * 4 + bt) * 64 + l) * 8);
#pragma unroll
    for (int ot = 0; ot < 4; ++ot)
#pragma unroll
      for (int bt = 0; bt < 4; ++bt)
        acc[ot][bt] = mfma16(a[ot], b[bt], acc[ot][bt]);  // A=W^T, B=h^T
    if (kt < 7) {
#pragma unroll
      for (int ot = 0; ot < 4; ++ot) a[ot] = an[ot];
    }
  }
  __syncthreads();  // all reads of hT done before in-place overwrite
  store_hT(acc, hT, wf, wb, li, g);
  __syncthreads();
}

__global__ __launch_bounds__(512, 4) void k_mlp(
    const unsigned short* __restrict__ sa,
    const unsigned short* __restrict__ w1,
    const unsigned short* __restrict__ w2,
    const unsigned short* __restrict__ w3,
    const unsigned short* __restrict__ w4,
    const float* __restrict__ bias,
    const int* __restrict__ flag,
    void* __restrict__ outp) {
  __shared__ __attribute__((aligned(16))) unsigned short hT[32768];  // 64 KB
  const int tid = threadIdx.x;
  const int w = tid >> 6, l = tid & 63, li = l & 15, g = l >> 4;
  const int wf = w & 3, wbk = w >> 2;
  const int bb = blockIdx.x;  // 128-row batch tile
  const int e  = blockIdx.y;  // ensemble
  const float* brow = bias + e * 816;
  const bool isbf = (*flag != 0);

  // ---- layer 1: W1^T(256x64) * sa^T(64x128) -> h1^T in LDS ----
  {
    floatx4 acc[4][4];
    bias_init(acc, brow, wf, g);
#pragma unroll
    for (int kt = 0; kt < 2; ++kt) {
      short8 a[4], b[4];
#pragma unroll
      for (int ot = 0; ot < 4; ++ot)
        a[ot] = *(const short8*)(w1 + (long)e * 16384 +
                                 (long)((kt * 16 + wf * 4 + ot) * 64 + l) * 8);
#pragma unroll
      for (int bt = 0; bt < 4; ++bt)
        b[bt] = *(const short8*)(sa + (long)((bb * 8 + wbk * 4 + bt) * 128 + kt * 64 + l) * 8);
#pragma unroll
      for (int ot = 0; ot < 4; ++ot)
#pragma unroll
        for (int bt = 0; bt < 4; ++bt)
          acc[ot][bt] = mfma16(a[ot], b[bt], acc[ot][bt]);
    }
    store_hT(acc, hT, wf, wbk, li, g);
    __syncthreads();
  }

  // ---- layers 2, 3 ----
  hidden_layer(w2 + (long)e * 65536, brow + 256, hT, wf, wbk, l, li, g);
  hidden_layer(w3 + (long)e * 65536, brow + 512, hT, wf, wbk, l, li, g);

  // ---- layer 4: W4^T(48x256) * h3^T(256x128), wave w owns batch tile w ----
  const float* brow4 = brow + 768;
  floatx4 acc4[3];
#pragma unroll
  for (int ot = 0; ot < 3; ++ot) {
    const float4 b4 = *(const float4*)(brow4 + ot * 16 + g * 4);
    acc4[ot] = (floatx4){b4.x, b4.y, b4.z, b4.w};
  }
#pragma unroll
  for (int kt = 0; kt < 8; ++kt) {
    short8 bfrag = *(const short8*)(hT + ((kt * 8 + w) * 64 + l) * 8);
#pragma unroll
    for (int ot = 0; ot < 3; ++ot) {
      short8 a = *(const short8*)(w4 + (long)e * 12288 + (long)((kt * 3 + ot) * 64 + l) * 8);
      acc4[ot] = mfma16(a, bfrag, acc4[ot]);
    }
  }

  // ---- output: lane holds out[feat=ot*16+g*4+r][batch=bb*128+w*16+li] ----
  const int batch = bb * 128 + w * 16 + li;
  const long nsbase = (long)(batch * NE + e) * 32;
  if (isbf) {
    unsigned short* o16 = (unsigned short*)outp;
#pragma unroll
    for (int ot = 0; ot < 2; ++ot) {
      unsigned d0 = pack_bf2(acc4[ot][0], acc4[ot][1]);
      unsigned d1 = pack_bf2(acc4[ot][2], acc4[ot][3]);
      *(unsigned long long*)(o16 + nsbase + ot * 16 + g * 4) =
          (unsigned long long)d0 | ((unsigned long long)d1 << 32);
    }
    if (g == 0) {  // reward = feat 32
      unsigned u = __float_as_uint(acc4[2][0]) + 0x8000u;
      o16[OUT_NS_ELEMS + batch * NE + e] = (unsigned short)(u >> 16);
    }
  } else {
    float* o32 = (float*)outp;
#pragma unroll
    for (int ot = 0; ot < 2; ++ot)
      *(float4*)(o32 + nsbase + ot * 16 + g * 4) =
          make_float4(acc4[ot][0], acc4[ot][1], acc4[ot][2], acc4[ot][3]);
    if (g == 0) o32[OUT_NS_ELEMS + batch * NE + e] = acc4[2][0];
  }
}

// ---------------------------------------------------------------------------
extern "C" void kernel_launch(void* const* d_in, const int* in_sizes, int n_in,
                              void* d_out, int out_size, void* d_ws, size_t ws_size,
                              hipStream_t stream) {
  const void* state  = d_in[0];
  const void* action = d_in[1];
  const void* W1 = d_in[2];
  const void* b1 = d_in[3];
  const void* W2 = d_in[4];
  const void* b2 = d_in[5];
  const void* W3 = d_in[6];
  const void* b3 = d_in[7];
  const void* W4 = d_in[8];
  const void* b4 = d_in[9];
  (void)in_sizes; (void)n_in; (void)out_size; (void)ws_size;

  char* ws = (char*)d_ws;
  int* flag              = (int*)(ws + 0);
  unsigned short* saP    = (unsigned short*)(ws + 256);        // 1,048,576 B
  unsigned short* w1P    = (unsigned short*)(ws + 1048832);    // 1,638,400 B
  unsigned short* w2P    = (unsigned short*)(ws + 2687232);    // 6,553,600 B
  unsigned short* w3P    = (unsigned short*)(ws + 9240832);    // 6,553,600 B
  unsigned short* w4P    = (unsigned short*)(ws + 15794432);   // 1,228,800 B
  float* biasP           = (float*)(ws + 17023232);            //   163,200 B

  k_detect<<<1, 256, 0, stream>>>((const unsigned*)W2, flag);
  k_pack<<<1716, 256, 0, stream>>>(state, action, W1, W2, W3, W4, b1, b2, b3, b4,
                                   flag, saP, w1P, w2P, w3P, w4P, biasP);
  k_mlp<<<dim3(64, 50), 512, 0, stream>>>(saP, w1P, w2P, w3P, w4P, biasP, flag, d_out);
}